// Round 1
// baseline (284.938 us; speedup 1.0000x reference)
//
#include <hip/hip_runtime.h>
#include <cstdint>
#include <cstddef>

namespace {

constexpr int LVL = 16;       // grid levels
constexpr int TSZ = 1 << 16;  // hash table size per level
constexpr uint32_t PRIME_Y = 2654435761u;
constexpr uint32_t PRIME_Z = 805459861u;
constexpr int OUTD = 71;      // 32 hash feats + 39 positional enc

__global__ __launch_bounds__(256) void hashgrid_enc_kernel(
    const float* __restrict__ x, const float* __restrict__ t,
    const int* __restrict__ mask, const int* __restrict__ layerid,
    const float* __restrict__ tables, const float* __restrict__ bbox,
    float* __restrict__ out, int n)
{
    const int i = blockIdx.x * blockDim.x + threadIdx.x;
    if (i >= n) return;

    // ---- uniform config: which 2 spatial dims are kept (mask has exactly one 0) ----
    const int m0 = mask[0];
    const int m2 = mask[2];
    // cases (0,1,1)->(1,2)  (1,0,1)->(0,2)  (1,1,0)->(0,1)
    const int k0 = m0 ? 0 : 1;
    const int k1 = m2 ? 2 : 1;

    // ---- load point ----
    const float xv0 = x[3 * (size_t)i + 0];
    const float xv1 = x[3 * (size_t)i + 1];
    const float xv2 = x[3 * (size_t)i + 2];
    const float xt0 = (k0 == 0) ? xv0 : xv1;
    const float xt1 = (k1 == 2) ? xv2 : xv1;
    const float xt2 = t[i];

    // ---- normalize into [0,1] ----
    const float lo0 = bbox[0], lo1 = bbox[1], lo2 = bbox[2];
    const float hi0 = bbox[3], hi1 = bbox[4], hi2 = bbox[5];
    float u0 = (xt0 - lo0) / (hi0 - lo0);
    float u1 = (xt1 - lo1) / (hi1 - lo1);
    float u2 = (xt2 - lo2) / (hi2 - lo2);
    u0 = fminf(fmaxf(u0, 0.f), 1.f);
    u1 = fminf(fmaxf(u1, 0.f), 1.f);
    u2 = fminf(fmaxf(u2, 0.f), 1.f);

    const float2* __restrict__ tab =
        reinterpret_cast<const float2*>(tables) + (size_t)layerid[0] * (LVL * (size_t)TSZ);

    float* __restrict__ orow = out + (size_t)i * OUTD;

    // ---- hash grid: 16 levels, trilinear over 8 corners ----
    // resolutions floor(16 * 32^(l/15)); levels fully unrolled so these fold to literals
    const float res_tab[LVL] = {16.f, 20.f, 25.f, 32.f, 40.f, 50.f, 64.f, 80.f,
                                101.f, 128.f, 161.f, 203.f, 256.f, 322.f, 406.f, 512.f};
#pragma unroll
    for (int l = 0; l < LVL; ++l) {
        const float r = res_tab[l];
        const float px = u0 * r, py = u1 * r, pz = u2 * r;
        const float f0x = floorf(px), f0y = floorf(py), f0z = floorf(pz);
        const float fx = px - f0x, fy = py - f0y, fz = pz - f0z;
        const uint32_t ix = (uint32_t)f0x;
        const uint32_t iy = (uint32_t)f0y;
        const uint32_t iz = (uint32_t)f0z;
        // per-axis partial hashes for the two corner planes
        const uint32_t hx0 = ix, hx1 = ix + 1u;                 // prime = 1
        const uint32_t hy0 = iy * PRIME_Y, hy1 = hy0 + PRIME_Y; // uint32 wraparound ok
        const uint32_t hz0 = iz * PRIME_Z, hz1 = hz0 + PRIME_Z;
        const float wx0 = 1.f - fx, wx1 = fx;
        const float wy0 = 1.f - fy, wy1 = fy;
        const float wz0 = 1.f - fz, wz1 = fz;
        const uint32_t base = (uint32_t)l * (uint32_t)TSZ;

        float a0 = 0.f, a1 = 0.f;
#pragma unroll
        for (int c = 0; c < 8; ++c) {
            const uint32_t cx = (c >> 2) & 1, cy = (c >> 1) & 1, cz = c & 1;
            const uint32_t h = (cx ? hx1 : hx0) ^ (cy ? hy1 : hy0) ^ (cz ? hz1 : hz0);
            const uint32_t idx = h & (uint32_t)(TSZ - 1);
            const float2 v = tab[base + idx];
            const float w = (cx ? wx1 : wx0) * (cy ? wy1 : wy0) * (cz ? wz1 : wz0);
            a0 = fmaf(w, v.x, a0);
            a1 = fmaf(w, v.y, a1);
        }
        orow[2 * l + 0] = a0;
        orow[2 * l + 1] = a1;
    }

    // ---- positional encoding: [x_t, sin(pi*2^f*x_t), cos(...)] f=0..5 ----
    orow[32] = xt0;
    orow[33] = xt1;
    orow[34] = xt2;
#pragma unroll
    for (int f = 0; f < 6; ++f) {
        // sin(pi * 2^f * x) = sin(2*pi * (x * 2^(f-1))); v_sin takes revolutions
        const float scale = (f == 0) ? 0.5f : (float)(1 << (f - 1));
        float r0 = xt0 * scale;
        float r1 = xt1 * scale;
        float r2 = xt2 * scale;
        r0 -= floorf(r0);
        r1 -= floorf(r1);
        r2 -= floorf(r2);
        const int o = 35 + 6 * f;
        orow[o + 0] = __builtin_amdgcn_sinf(r0);
        orow[o + 1] = __builtin_amdgcn_sinf(r1);
        orow[o + 2] = __builtin_amdgcn_sinf(r2);
        orow[o + 3] = __builtin_amdgcn_cosf(r0);
        orow[o + 4] = __builtin_amdgcn_cosf(r1);
        orow[o + 5] = __builtin_amdgcn_cosf(r2);
    }
}

} // namespace

extern "C" void kernel_launch(void* const* d_in, const int* in_sizes, int n_in,
                              void* d_out, int out_size, void* d_ws, size_t ws_size,
                              hipStream_t stream) {
    const float* x       = (const float*)d_in[0];
    const float* t       = (const float*)d_in[1];
    const int*   mask    = (const int*)d_in[2];
    const int*   layerid = (const int*)d_in[3];
    const float* tables  = (const float*)d_in[4];
    const float* bbox    = (const float*)d_in[5];
    float*       out     = (float*)d_out;

    const int n = in_sizes[0] / 3;
    const int threads = 256;
    const int blocks = (n + threads - 1) / threads;
    hipLaunchKernelGGL(hashgrid_enc_kernel, dim3(blocks), dim3(threads), 0, stream,
                       x, t, mask, layerid, tables, bbox, out, n);
}

// Round 2
// 268.965 us; speedup vs baseline: 1.0594x; 1.0594x over previous
//
#include <hip/hip_runtime.h>
#include <cstdint>
#include <cstddef>

namespace {

constexpr int LVL = 16;       // grid levels
constexpr int TSZ = 1 << 16;  // hash table size per level
constexpr uint32_t PRIME_Y = 2654435761u;
constexpr uint32_t PRIME_Z = 805459861u;
constexpr int OUTD = 71;      // 32 hash feats + 39 positional enc
constexpr int CA = 36;        // chunk A = cols 0..35  (32 hash + xt0..2 + sin_f0_d0)
constexpr int SA = 37;        // LDS stride A (odd mod 32 -> conflict-free)
constexpr int CB = 35;        // chunk B = cols 36..70
constexpr int SB = 35;        // LDS stride B (35 mod 32 = 3 -> conflict-free)

__device__ __forceinline__ float fract1(float v) { return v - floorf(v); }

__global__ __launch_bounds__(256, 4) void hashgrid_enc_kernel(
    const float* __restrict__ x, const float* __restrict__ t,
    const int* __restrict__ mask, const int* __restrict__ layerid,
    const float* __restrict__ tables, const float* __restrict__ bbox,
    float* __restrict__ out, int n)
{
    __shared__ float lds[256 * SA];   // 37,888 B; reused for chunk A then chunk B

    const int lane = threadIdx.x & 63;
    const int wave = threadIdx.x >> 6;
    const int rowbase = blockIdx.x * 256 + wave * 64;   // first point of this wave
    const int gid = rowbase + lane;
    const int i = (gid < n) ? gid : (n - 1);            // clamp: all threads reach barriers

    float* __restrict__ wlds = lds + wave * 64 * SA;

    // ---- uniform config: which 2 spatial dims are kept (mask has exactly one 0) ----
    const int m0 = mask[0];
    const int m2 = mask[2];
    const int k0 = m0 ? 0 : 1;
    const int k1 = m2 ? 2 : 1;

    // ---- load point ----
    const float xv0 = x[3 * (size_t)i + 0];
    const float xv1 = x[3 * (size_t)i + 1];
    const float xv2 = x[3 * (size_t)i + 2];
    const float xt0 = (k0 == 0) ? xv0 : xv1;
    const float xt1 = (k1 == 2) ? xv2 : xv1;
    const float xt2 = t[i];

    // ---- normalize into [0,1] ----
    const float lo0 = bbox[0], lo1 = bbox[1], lo2 = bbox[2];
    const float hi0 = bbox[3], hi1 = bbox[4], hi2 = bbox[5];
    float u0 = fminf(fmaxf((xt0 - lo0) / (hi0 - lo0), 0.f), 1.f);
    float u1 = fminf(fmaxf((xt1 - lo1) / (hi1 - lo1), 0.f), 1.f);
    float u2 = fminf(fmaxf((xt2 - lo2) / (hi2 - lo2), 0.f), 1.f);

    const float2* __restrict__ tab =
        reinterpret_cast<const float2*>(tables) + (size_t)layerid[0] * (LVL * (size_t)TSZ);

    // ================= phase A: hash grid (cols 0..31) + cols 32..35 =================
    const float res_tab[LVL] = {16.f, 20.f, 25.f, 32.f, 40.f, 50.f, 64.f, 80.f,
                                101.f, 128.f, 161.f, 203.f, 256.f, 322.f, 406.f, 512.f};
#pragma unroll
    for (int l = 0; l < LVL; ++l) {
        const float r = res_tab[l];
        const float px = u0 * r, py = u1 * r, pz = u2 * r;
        const float f0x = floorf(px), f0y = floorf(py), f0z = floorf(pz);
        const float fx = px - f0x, fy = py - f0y, fz = pz - f0z;
        const uint32_t ix = (uint32_t)f0x;
        const uint32_t iy = (uint32_t)f0y;
        const uint32_t iz = (uint32_t)f0z;
        const uint32_t hx0 = ix, hx1 = ix + 1u;
        const uint32_t hy0 = iy * PRIME_Y, hy1 = hy0 + PRIME_Y;
        const uint32_t hz0 = iz * PRIME_Z, hz1 = hz0 + PRIME_Z;
        const float wx0 = 1.f - fx, wx1 = fx;
        const float wy0 = 1.f - fy, wy1 = fy;
        const float wz0 = 1.f - fz, wz1 = fz;
        const uint32_t base = (uint32_t)l * (uint32_t)TSZ;

        float a0 = 0.f, a1 = 0.f;
#pragma unroll
        for (int c = 0; c < 8; ++c) {
            const uint32_t cx = (c >> 2) & 1, cy = (c >> 1) & 1, cz = c & 1;
            const uint32_t h = (cx ? hx1 : hx0) ^ (cy ? hy1 : hy0) ^ (cz ? hz1 : hz0);
            const uint32_t idx = h & (uint32_t)(TSZ - 1);
            const float2 v = tab[base + idx];
            const float w = (cx ? wx1 : wx0) * (cy ? wy1 : wy0) * (cz ? wz1 : wz0);
            a0 = fmaf(w, v.x, a0);
            a1 = fmaf(w, v.y, a1);
        }
        wlds[lane * SA + 2 * l + 0] = a0;
        wlds[lane * SA + 2 * l + 1] = a1;
    }
    wlds[lane * SA + 32] = xt0;
    wlds[lane * SA + 33] = xt1;
    wlds[lane * SA + 34] = xt2;
    wlds[lane * SA + 35] = __builtin_amdgcn_sinf(fract1(xt0 * 0.5f));  // sin(pi*xt0)

    __syncthreads();

    // ---- flush A: 64x36 sub-block of the row-major 64x71 output region ----
    {
        float* __restrict__ obase = out + (size_t)rowbase * OUTD;
        const int rows_valid = n - rowbase;   // may exceed 64 (fine) or be <= 0
#pragma unroll
        for (int it = 0; it < CA; ++it) {
            const int k = it * 64 + lane;
            const int r = k / CA;
            const int c = k - r * CA;
            if (r < rows_valid)
                obase[(size_t)r * OUTD + c] = wlds[r * SA + c];
        }
    }

    __syncthreads();   // buffer reuse

    // ================= phase B: positional encoding cols 36..70 =================
    // col layout: f in 0..5 -> o = 35+6f: sin d0,d1,d2 at o..o+2, cos at o+3..o+5
    {
        float* __restrict__ wb = lds + wave * 64 * SB;   // stride 35 region (same buffer)
#pragma unroll
        for (int f = 0; f < 6; ++f) {
            const float scale = (f == 0) ? 0.5f : (float)(1 << (f - 1));
            const float r0 = fract1(xt0 * scale);
            const float r1 = fract1(xt1 * scale);
            const float r2 = fract1(xt2 * scale);
            const float s0 = __builtin_amdgcn_sinf(r0);
            const float s1 = __builtin_amdgcn_sinf(r1);
            const float s2 = __builtin_amdgcn_sinf(r2);
            const float c0 = __builtin_amdgcn_cosf(r0);
            const float c1 = __builtin_amdgcn_cosf(r1);
            const float c2 = __builtin_amdgcn_cosf(r2);
            const int o = 35 + 6 * f;        // global col of sin d0
            // chunk-B local col = global col - 36
            if (f != 0) wb[lane * SB + (o - 36)] = s0;   // f==0 sin d0 lives in chunk A
            wb[lane * SB + (o + 1 - 36)] = s1;
            wb[lane * SB + (o + 2 - 36)] = s2;
            wb[lane * SB + (o + 3 - 36)] = c0;
            wb[lane * SB + (o + 4 - 36)] = c1;
            wb[lane * SB + (o + 5 - 36)] = c2;
        }
    }

    __syncthreads();

    // ---- flush B: 64x35 sub-block, cols 36..70 ----
    {
        float* __restrict__ wb = lds + wave * 64 * SB;
        float* __restrict__ obase = out + (size_t)rowbase * OUTD;
        const int rows_valid = n - rowbase;
#pragma unroll
        for (int it = 0; it < CB; ++it) {
            const int k = it * 64 + lane;
            const int r = k / CB;
            const int c = k - r * CB;
            if (r < rows_valid)
                obase[(size_t)r * OUTD + 36 + c] = wb[r * SB + c];
        }
    }
}

} // namespace

extern "C" void kernel_launch(void* const* d_in, const int* in_sizes, int n_in,
                              void* d_out, int out_size, void* d_ws, size_t ws_size,
                              hipStream_t stream) {
    const float* x       = (const float*)d_in[0];
    const float* t       = (const float*)d_in[1];
    const int*   mask    = (const int*)d_in[2];
    const int*   layerid = (const int*)d_in[3];
    const float* tables  = (const float*)d_in[4];
    const float* bbox    = (const float*)d_in[5];
    float*       out     = (float*)d_out;

    const int n = in_sizes[0] / 3;
    const int threads = 256;
    const int blocks = (n + threads - 1) / threads;
    hipLaunchKernelGGL(hashgrid_enc_kernel, dim3(blocks), dim3(threads), 0, stream,
                       x, t, mask, layerid, tables, bbox, out, n);
}

// Round 3
// 155.378 us; speedup vs baseline: 1.8338x; 1.7310x over previous
//
#include <hip/hip_runtime.h>
#include <cstdint>
#include <cstddef>

namespace {

constexpr int LVL = 16;       // grid levels
constexpr int TSZ = 1 << 16;  // hash table size per level
constexpr uint32_t PRIME_Y = 2654435761u;
constexpr uint32_t PRIME_Z = 805459861u;
constexpr int OUTD = 71;      // 32 hash feats + 39 positional enc
constexpr int PPW = 32;       // points per wave (2 lanes per point)
constexpr int PPB = 128;      // points per block (4 waves)
constexpr int SROW = 73;      // LDS row stride (odd -> conflict-free scattered writes)

__device__ __forceinline__ float fract1(float v) { return v - floorf(v); }

// ---- pre-pass: convert active layer's table f32[2] -> packed bf16 dword ----
__global__ __launch_bounds__(256) void convert_table_kernel(
    const float* __restrict__ tables, const int* __restrict__ layerid,
    uint32_t* __restrict__ tab_bf16)
{
    const float* __restrict__ src = tables + (size_t)layerid[0] * (2u * LVL * (size_t)TSZ);
    const int n_entries = LVL * TSZ;  // 1M entries (2 floats each)
    int i = blockIdx.x * blockDim.x + threadIdx.x;
    const int stride = gridDim.x * blockDim.x;
    for (; i < n_entries; i += stride) {
        const uint32_t lo = __float_as_uint(src[2 * i + 0]);
        const uint32_t hi = __float_as_uint(src[2 * i + 1]);
        tab_bf16[i] = (lo >> 16) | (hi & 0xFFFF0000u);  // truncate-to-bf16, err <= 2^-8 rel
    }
}

template <bool BF16TAB>
__global__ __launch_bounds__(256, 4) void hashgrid_enc_kernel(
    const float* __restrict__ x, const float* __restrict__ t,
    const int* __restrict__ mask, const int* __restrict__ layerid,
    const float* __restrict__ tables, const uint32_t* __restrict__ tab_bf16,
    const float* __restrict__ bbox,
    float* __restrict__ out, int n)
{
    __shared__ float lds[4 * PPW * SROW];   // 37,376 B -> 4 blocks/CU

    const int lane = threadIdx.x & 63;
    const int wave = threadIdx.x >> 6;
    const uint32_t half = (uint32_t)(lane & 1);      // which 4 corners this lane owns
    const int rowbase = blockIdx.x * PPB + wave * PPW;
    const int p = rowbase + (lane >> 1);
    const int i = (p < n) ? p : (n - 1);             // clamp; flush is guarded

    // ---- uniform config ----
    const int m0 = mask[0];
    const int m2 = mask[2];
    const int k0 = m0 ? 0 : 1;
    const int k1 = m2 ? 2 : 1;

    // ---- load point ----
    const float xv0 = x[3 * (size_t)i + 0];
    const float xv1 = x[3 * (size_t)i + 1];
    const float xv2 = x[3 * (size_t)i + 2];
    const float xt0 = (k0 == 0) ? xv0 : xv1;
    const float xt1 = (k1 == 2) ? xv2 : xv1;
    const float xt2 = t[i];

    const float lo0 = bbox[0], lo1 = bbox[1], lo2 = bbox[2];
    const float hi0 = bbox[3], hi1 = bbox[4], hi2 = bbox[5];
    const float u0 = fminf(fmaxf((xt0 - lo0) / (hi0 - lo0), 0.f), 1.f);
    const float u1 = fminf(fmaxf((xt1 - lo1) / (hi1 - lo1), 0.f), 1.f);
    const float u2 = fminf(fmaxf((xt2 - lo2) / (hi2 - lo2), 0.f), 1.f);

    const float2* __restrict__ tabf = BF16TAB ? nullptr
        : reinterpret_cast<const float2*>(tables) + (size_t)layerid[0] * (LVL * (size_t)TSZ);

    const float res_tab[LVL] = {16.f, 20.f, 25.f, 32.f, 40.f, 50.f, 64.f, 80.f,
                                101.f, 128.f, 161.f, 203.f, 256.f, 322.f, 406.f, 512.f};

    // ---- hash grid: 16 levels, 4 corners/lane, 2-level software pipeline ----
    float feat0[LVL], feat1[LVL];
    float    pw[2][4];     // pipeline: trilinear weights
    uint32_t pv[2][4];     // pipeline: packed-bf16 values
    float2   pvf[2][4];    // pipeline: f32 values (fallback path)

#pragma unroll
    for (int l = 0; l < LVL; ++l) { feat0[l] = 0.f; feat1[l] = 0.f; }

#pragma unroll
    for (int l = 0; l <= LVL; ++l) {
        if (l < LVL) {
            // issue level l into slot l&1
            const float r = res_tab[l];
            const float px = u0 * r, py = u1 * r, pz = u2 * r;
            const float f0x = floorf(px), f0y = floorf(py), f0z = floorf(pz);
            const float fx = px - f0x, fy = py - f0y, fz = pz - f0z;
            const uint32_t hx  = (uint32_t)f0x + half;               // prime = 1
            const uint32_t hyA = (uint32_t)f0y * PRIME_Y, hyB = hyA + PRIME_Y;
            const uint32_t hzA = (uint32_t)f0z * PRIME_Z, hzB = hzA + PRIME_Z;
            const float wx = half ? fx : 1.f - fx;
            const uint32_t base = (uint32_t)l * (uint32_t)TSZ;
#pragma unroll
            for (int c = 0; c < 4; ++c) {
                const uint32_t h = hx ^ ((c & 2) ? hyB : hyA) ^ ((c & 1) ? hzB : hzA);
                const uint32_t idx = (h & (uint32_t)(TSZ - 1)) + base;
                pw[l & 1][c] = wx * ((c & 2) ? fy : 1.f - fy) * ((c & 1) ? fz : 1.f - fz);
                if constexpr (BF16TAB) pv[l & 1][c] = tab_bf16[idx];
                else                   pvf[l & 1][c] = tabf[idx];
            }
        }
        if (l > 0) {
            // consume level l-1 from slot (l-1)&1
            const int s = (l - 1) & 1;
            float a0 = 0.f, a1 = 0.f;
#pragma unroll
            for (int c = 0; c < 4; ++c) {
                float v0, v1;
                if constexpr (BF16TAB) {
                    const uint32_t w = pv[s][c];
                    v0 = __uint_as_float(w << 16);
                    v1 = __uint_as_float(w & 0xFFFF0000u);
                } else {
                    v0 = pvf[s][c].x; v1 = pvf[s][c].y;
                }
                a0 = fmaf(pw[s][c], v0, a0);
                a1 = fmaf(pw[s][c], v1, a1);
            }
            feat0[l - 1] = a0;
            feat1[l - 1] = a1;
        }
    }

    // ---- pair-combine: each point's two lanes sum their 4-corner partials ----
#pragma unroll
    for (int l = 0; l < LVL; ++l) {
        feat0[l] += __shfl_xor(feat0[l], 1);
        feat1[l] += __shfl_xor(feat1[l], 1);
    }

    // ---- stage full 71-col rows in LDS: even lane hash feats, odd lane PE ----
    float* __restrict__ wrow = lds + (wave * PPW + (lane >> 1)) * SROW;
    if (half == 0) {
#pragma unroll
        for (int l = 0; l < LVL; ++l) {
            wrow[2 * l + 0] = feat0[l];
            wrow[2 * l + 1] = feat1[l];
        }
    } else {
        wrow[32] = xt0;
        wrow[33] = xt1;
        wrow[34] = xt2;
#pragma unroll
        for (int f = 0; f < 6; ++f) {
            const float scale = (f == 0) ? 0.5f : (float)(1 << (f - 1));
            const float r0 = fract1(xt0 * scale);
            const float r1 = fract1(xt1 * scale);
            const float r2 = fract1(xt2 * scale);
            const int o = 35 + 6 * f;
            wrow[o + 0] = __builtin_amdgcn_sinf(r0);
            wrow[o + 1] = __builtin_amdgcn_sinf(r1);
            wrow[o + 2] = __builtin_amdgcn_sinf(r2);
            wrow[o + 3] = __builtin_amdgcn_cosf(r0);
            wrow[o + 4] = __builtin_amdgcn_cosf(r1);
            wrow[o + 5] = __builtin_amdgcn_cosf(r2);
        }
    }

    __syncthreads();

    // ---- flush: 32 complete rows = 9088 B = 71 full cache lines, line-aligned ----
    {
        float* __restrict__ obase = out + (size_t)rowbase * OUTD;
        const float* __restrict__ wlds = lds + wave * PPW * SROW;
        const int rows_valid = n - rowbase;
#pragma unroll
        for (int it = 0; it < 36; ++it) {
            const int k = it * 64 + lane;
            if (k < PPW * OUTD) {
                const int r = k / OUTD;
                const int c = k - r * OUTD;
                if (r < rows_valid)
                    obase[k] = wlds[r * SROW + c];
            }
        }
    }
}

} // namespace

extern "C" void kernel_launch(void* const* d_in, const int* in_sizes, int n_in,
                              void* d_out, int out_size, void* d_ws, size_t ws_size,
                              hipStream_t stream) {
    const float* x       = (const float*)d_in[0];
    const float* t       = (const float*)d_in[1];
    const int*   mask    = (const int*)d_in[2];
    const int*   layerid = (const int*)d_in[3];
    const float* tables  = (const float*)d_in[4];
    const float* bbox    = (const float*)d_in[5];
    float*       out     = (float*)d_out;

    const int n = in_sizes[0] / 3;
    const int blocks = (n + PPB - 1) / PPB;
    const size_t tab_bytes = (size_t)LVL * TSZ * 4;   // 4 MB packed bf16

    if (ws_size >= tab_bytes) {
        uint32_t* tab_bf16 = (uint32_t*)d_ws;
        hipLaunchKernelGGL(convert_table_kernel, dim3(4096), dim3(256), 0, stream,
                           tables, layerid, tab_bf16);
        hipLaunchKernelGGL((hashgrid_enc_kernel<true>), dim3(blocks), dim3(256), 0, stream,
                           x, t, mask, layerid, tables, tab_bf16, bbox, out, n);
    } else {
        hipLaunchKernelGGL((hashgrid_enc_kernel<false>), dim3(blocks), dim3(256), 0, stream,
                           x, t, mask, layerid, tables, nullptr, bbox, out, n);
    }
}